// Round 10
// baseline (219.562 us; speedup 1.0000x reference)
//
#include <hip/hip_runtime.h>

// GaussianPooling: fm[512,256,256] f32, keypoints[4096,2] int, out[4096,512] f32.
// 5x5 gaussian sigma=2, separable: k = g(dy)*g(dx)/s^2.
//
// R10 = R7's persistent-ring skeleton + the two parasites fixed:
//  - R7 counters: WRITE_SIZE 86 MB for 8.4 MB out (16 channel-blocks on
//    different XCDs partially writing each 64B line) and 7.4M LDS-conflict
//    cycles (ring stride 256 = bank-aligned). Its read stream ran ~3.9 TB/s
//    -- better than any slice-cohort variant (~2.1 TB/s, 25% halo refetch).
//  - Fixes: ring stride 260 (bank-rotate, 16B-aligned), and channel swizzle
//    b = (chunk&7) + 8*(lane + 16*(chunk>>3)) so all 16 writers of an
//    out-line share b%8 -> same XCD -> dword stores merge in its L2.
//  - 512 persistent blocks (2/CU), 8-row strips (32), ring 32 rows x 260 fl
//    = 33,280 B. fm fetched exactly once (128 MB, zero halo). Software
//    pipeline: prefetch strip s+2 to VGPRs / compute strip s from ring /
//    barrier / commit s+2 / barrier.
//  - Bucket: single 1024-thread block, strided per-strip lists (no scan, no
//    memset launch).

#define NC  512
#define NH  256
#define NW  256
#define NKP 4096

#define NSTRIP 32              // y-strips of 8 rows
#define RING_ROWS 32
#define STR 260                // ring row stride (floats): +4 rotates banks, keeps 16B align

// ws layout (int32 offsets):
//   [0..32)                    cnt[32]
//   [8192 .. 8192+32*NKP)      packed lists (i | x<<12 | y<<20), stride NKP
#define WS_LIST_OFF_I 8192

// ---------------- bucket: single block, strided lists, no scan ----------------
__global__ __launch_bounds__(1024) void bucket_kernel(
    const int* __restrict__ kp, unsigned* __restrict__ ws_i, int n_kp)
{
    __shared__ int hist[NSTRIP];
    const int t = threadIdx.x;
    if (t < NSTRIP) hist[t] = 0;
    __syncthreads();

#pragma unroll
    for (int k = 0; k < 4; ++k) {
        const int i = t + k * 1024;
        if (i < n_kp) {
            int x = kp[2 * i + 0];
            int y = kp[2 * i + 1];
            x = min(max(x, 2), NW - 3);
            y = min(max(y, 2), NH - 3);
            const int q = y >> 3;                       // 8-row strips
            const int pos = atomicAdd(&hist[q], 1);
            ws_i[WS_LIST_OFF_I + q * NKP + pos] =
                (unsigned)i | ((unsigned)x << 12) | ((unsigned)y << 20);
        }
    }
    __syncthreads();
    if (t < NSTRIP) ws_i[t] = (unsigned)hist[t];
}

// ---------------- pool: 512 persistent channel-blocks, LDS ring pipeline ----------------
__global__ __launch_bounds__(256) void pool_kernel(
    const float* __restrict__ fm, const unsigned* __restrict__ ws_i,
    float* __restrict__ out)
{
    __shared__ float ring[RING_ROWS * STR];   // 33,280 B -> 2 blocks/CU (by grid)

    // swizzle: b = (chunk&7) + 8*(lane + 16*(chunk>>3));  c = chunk*16 + lane
    const int b      = blockIdx.x;            // 0..511
    const int x7     = b & 7;
    const int inner  = b >> 3;                // 0..63
    const int lane16 = inner & 15;
    const int hi     = inner >> 4;            // 0..3
    const int chunk  = (hi << 3) | x7;        // 0..31
    const int c      = (chunk << 4) | lane16; // 0..511

    const int t = threadIdx.x;
    const float4* src = (const float4*)(fm + ((size_t)c << 16));  // 16384 float4

    // gaussian weights
    const float e1 = 0.8824969025845955f;  // exp(-1/8)
    const float e2 = 0.6065306597126334f;  // exp(-4/8)
    const float sN = 2.0f * (e1 + e2) + 1.0f;
    const float inv_s2 = 1.0f / (sN * sN);
    const float g[5] = {e2, e1, 1.0f, e1, e2};
    float gy[5];
#pragma unroll
    for (int i = 0; i < 5; i++) gy[i] = g[i] * inv_s2;

    float4 pf0, pf1;   // prefetch: strip = 8 rows * 64 float4 = 512; 2/thread

    for (int s = -2; s < NSTRIP; ++s) {
        const int sp = s + 2;

        // 1) prefetch strip sp into VGPRs (consumed only after compute+barrier)
        if (sp < NSTRIP) {
            pf0 = src[(sp << 9) + t];
            pf1 = src[(sp << 9) + 256 + t];
        }

        // 2) compute strip s from ring (rows 8s-2 .. 8s+9 resident)
        if (s >= 0) {
            const int cnt = (int)ws_i[s];
            const unsigned* list = ws_i + WS_LIST_OFF_I + s * NKP;
            for (int e = t; e < cnt; e += 256) {
                const unsigned pk = list[e];
                const int n  = (int)(pk & 0xFFFu);
                const int xc = (int)((pk >> 12) & 0xFFu);
                const int yc = (int)((pk >> 20) & 0xFFu);

                const int x0 = xc - 2;
                const int r  = x0 & 3;
                const int xa = x0 - r;
                float wx[8];
#pragma unroll
                for (int i = 0; i < 8; i++)
                    wx[i] = (i >= r && i < r + 5) ? g[i - r] : 0.0f;

                float acc = 0.0f;
#pragma unroll
                for (int dy = 0; dy < 5; dy++) {
                    const int gr = yc - 2 + dy;
                    const float* rowp = &ring[(gr & (RING_ROWS - 1)) * STR + xa];
                    float4 a  = *(const float4*)rowp;
                    float4 b4 = *(const float4*)(rowp + 4);
                    acc += gy[dy] * (a.x * wx[0] + a.y * wx[1] + a.z * wx[2] + a.w * wx[3]
                                   + b4.x * wx[4] + b4.y * wx[5] + b4.z * wx[6] + b4.w * wx[7]);
                }
                out[(size_t)n * NC + c] = acc;   // merges into full lines in same-XCD L2
            }
        }

        __syncthreads();   // all waves done reading before ring slots are overwritten

        // 3) commit prefetched strip sp (rows 8sp..8sp+7 -> ring rows mod 32)
        if (sp < NSTRIP) {
            {
                const int row  = t >> 6;              // 0..3
                const int col4 = t & 63;
                const int pr   = ((sp << 3) + row) & (RING_ROWS - 1);
                *(float4*)&ring[pr * STR + (col4 << 2)] = pf0;
            }
            {
                const int j    = t + 256;
                const int row  = j >> 6;              // 4..7
                const int col4 = j & 63;
                const int pr   = ((sp << 3) + row) & (RING_ROWS - 1);
                *(float4*)&ring[pr * STR + (col4 << 2)] = pf1;
            }
        }

        __syncthreads();
    }
}

// ---------------- fallback (round-1 direct kernel) ----------------
__global__ __launch_bounds__(256) void gpool_direct_kernel(
    const float* __restrict__ fm, const int* __restrict__ kp,
    float* __restrict__ out)
{
    const int n = blockIdx.x;
    const int t = threadIdx.x;

    int x = kp[2 * n + 0];
    int y = kp[2 * n + 1];
    x = min(max(x, 2), NW - 3);
    y = min(max(y, 2), NH - 3);

    const float e1 = 0.8824969025845955f;
    const float e2 = 0.6065306597126334f;
    const float s  = 2.0f * (e1 + e2) + 1.0f;
    const float inv_s2 = 1.0f / (s * s);
    float g[5] = {e2, e1, 1.0f, e1, e2};
    float gy[5];
#pragma unroll
    for (int i = 0; i < 5; i++) gy[i] = g[i] * inv_s2;

    const int x0 = x - 2;
    const int r  = x0 & 3;
    const int xa = x0 - r;
    float wx[8];
#pragma unroll
    for (int i = 0; i < 8; i++)
        wx[i] = (i >= r && i < r + 5) ? g[i - r] : 0.0f;

    const float* base0 = fm + ((size_t)t * NH + (y - 2)) * NW + xa;
    const float* base1 = fm + ((size_t)(t + 256) * NH + (y - 2)) * NW + xa;

    float acc0 = 0.0f, acc1 = 0.0f;
#pragma unroll
    for (int dy = 0; dy < 5; dy++) {
        const float4* p0 = (const float4*)(base0 + dy * NW);
        const float4* p1 = (const float4*)(base1 + dy * NW);
        float4 a0 = p0[0], b0 = p0[1], a1 = p1[0], b1 = p1[1];
        acc0 += gy[dy] * (a0.x * wx[0] + a0.y * wx[1] + a0.z * wx[2] + a0.w * wx[3]
                        + b0.x * wx[4] + b0.y * wx[5] + b0.z * wx[6] + b0.w * wx[7]);
        acc1 += gy[dy] * (a1.x * wx[0] + a1.y * wx[1] + a1.z * wx[2] + a1.w * wx[3]
                        + b1.x * wx[4] + b1.y * wx[5] + b1.z * wx[6] + b1.w * wx[7]);
    }

    out[(size_t)n * NC + t]       = acc0;
    out[(size_t)n * NC + t + 256] = acc1;
}

extern "C" void kernel_launch(void* const* d_in, const int* in_sizes, int n_in,
                              void* d_out, int out_size, void* d_ws, size_t ws_size,
                              hipStream_t stream)
{
    const float* fm  = (const float*)d_in[0];
    const int*   kp  = (const int*)d_in[1];
    float*       out = (float*)d_out;
    const int n_kp   = in_sizes[1] / 2;   // 4096

    const size_t need = (WS_LIST_OFF_I + (size_t)NSTRIP * NKP) * sizeof(unsigned);
    if (ws_size >= need && n_kp == NKP) {
        unsigned* ws_i = (unsigned*)d_ws;

        bucket_kernel<<<1, 1024, 0, stream>>>(kp, ws_i, n_kp);
        pool_kernel<<<NC, 256, 0, stream>>>(fm, ws_i, out);
    } else {
        gpool_direct_kernel<<<n_kp, 256, 0, stream>>>(fm, kp, out);
    }
}